// Round 1
// baseline (387.600 us; speedup 1.0000x reference)
//
#include <hip/hip_runtime.h>

// NonLocalBlock, B=4, C=64, H=W=64, N=4096, Ch=32.
//
// Index algebra (verified against reference):
//  x1[b,i,c]  = conv1_flat[b][i*32+c]      -> conv1 natural [ch][hw] buffer IS x1 flat
//  x2[b,k,j]  = conv2[b][k][j]             -> natural
//  y3[b,j,c]  = conv3_flat[b][j*32+c]      -> conv3 natural buffer IS y3 flat
//  attn[b,i,j] = sum_k x1[b,i,k]*x2[b,k,j];  softmax over axis 0 (batch, 4 elems, per (i,j))
//  O[b,i,c]   = sum_j attn[b,i,j]*y3[b,j,c]
//  y2[b,ch,hw] = O_flat[b][ch*4096+hw]     -> O flat read directly by conv4
//  out[b,o,hw] = b4[o] + sum_ch w4[o,ch]*y2[b,ch,hw]

#define N_PIX 4096
#define CIN   64
#define CHD   32
#define NB    4
#define TI    32
#define TJ    32
#define JS    4
#define ITERS ((N_PIX / JS) / TJ)   // 32

// ws layout (floats):
//  X1 @ 0        [4][4096][32] (= conv1 natural flat)
//  X2 @ 524288   [4][32][4096]
//  Y3 @ 1048576  [4][4096][32] (= conv3 natural flat)
//  OP @ 1572864  [JS][4][4096][32]  partial O per j-chunk
// total = 14.7 MB

__global__ __launch_bounds__(256) void convs_kernel(
    const float* __restrict__ x,
    const float* __restrict__ w1, const float* __restrict__ b1,
    const float* __restrict__ w2, const float* __restrict__ b2,
    const float* __restrict__ w3, const float* __restrict__ b3,
    float* __restrict__ X1, float* __restrict__ X2, float* __restrict__ Y3)
{
    const int t = blockIdx.y;                  // which conv (0..2)
    const float* w  = (t == 0) ? w1 : ((t == 1) ? w2 : w3);
    const float* bb = (t == 0) ? b1 : ((t == 1) ? b2 : b3);
    float* dst      = (t == 0) ? X1 : ((t == 1) ? X2 : Y3);

    __shared__ float sw[CHD][CIN];             // 8 KB
    __shared__ float sbias[CHD];
    const int tid = threadIdx.x;
    for (int e = tid; e < CHD * CIN; e += 256) sw[e >> 6][e & 63] = w[e];
    if (tid < CHD) sbias[tid] = bb[tid];
    __syncthreads();

    const int b  = blockIdx.x >> 4;
    const int hw = ((blockIdx.x & 15) << 8) + tid;

    float xi[CIN];
    const float* xb = x + b * CIN * N_PIX + hw;
    #pragma unroll
    for (int c = 0; c < CIN; c++) xi[c] = xb[c * N_PIX];

    float* db = dst + b * CHD * N_PIX + hw;
    for (int o = 0; o < CHD; o++) {
        float a0 = sbias[o], a1 = 0.f, a2 = 0.f, a3 = 0.f;
        #pragma unroll
        for (int c = 0; c < CIN; c += 4) {
            a0 += xi[c + 0] * sw[o][c + 0];
            a1 += xi[c + 1] * sw[o][c + 1];
            a2 += xi[c + 2] * sw[o][c + 2];
            a3 += xi[c + 3] * sw[o][c + 3];
        }
        db[o * N_PIX] = (a0 + a1) + (a2 + a3);   // natural [ch][hw] write, coalesced
    }
}

// Fused attn: s = X1 x X2 (K=32), softmax over batch (register-local), O += P x Y3.
// Thread map stage1: ii=tid>>4 -> i=2*ii+{0,1}; jj=tid&15 -> j=2*jj+{0,1}; all 4 b per thread.
// Thread map stage2: same ii for i; jj plays c: c=2*jj+{0,1}.
__global__ __launch_bounds__(256) void attn_kernel(
    const float* __restrict__ X1, const float* __restrict__ X2,
    const float* __restrict__ Y3, float* __restrict__ OP)
{
    __shared__ float sX1[NB][CHD][34];   // [b][k][i], pad 34: staging transpose conflict-free
    __shared__ float sY3[NB][TJ][CHD];   // [b][jl][c]
    __shared__ float sU[NB * TJ * 34];   // union: X2 view [(b*32+k)*32+jl] | P view [(b*32+j)*34+il]

    const int tid = threadIdx.x;
    const int ib  = blockIdx.x >> 2;            // 0..127
    const int jc  = blockIdx.x & 3;             // 0..3
    const int i0  = ib * TI;
    const int jch = jc * (N_PIX / JS);          // jc*1024
    const int ii  = tid >> 4;                   // 0..15
    const int jj  = tid & 15;                   // 0..15

    // stage X1 tile (transpose [i][k] -> [k][i])
    for (int b = 0; b < NB; b++)
        for (int r = 0; r < 4; r++) {
            int e  = r * 256 + tid;             // 0..1023
            int il = e >> 5, k = e & 31;
            sX1[b][k][il] = X1[b * 131072 + (i0 + il) * 32 + k];
        }

    float o_acc[NB][2][2] = {};                 // [b][di][dc]

    for (int it = 0; it < ITERS; it++) {
        const int jb = jch + it * TJ;
        __syncthreads();                        // prior stage2 done with sU/sY3 (also covers sX1 staging)
        {   // stage X2 tile -> sU (x2 view), Y3 tile -> sY3. 1 float4 per b per thread each.
            const int k  = tid >> 3;
            const int jl = (tid & 7) << 2;
            float* sy = &sY3[0][0][0];
            #pragma unroll
            for (int b = 0; b < NB; b++) {
                float4 v = *(const float4*)&X2[b * 131072 + k * 4096 + jb + jl];
                *(float4*)&sU[(b * 32 + k) * 32 + jl] = v;
                float4 u = *(const float4*)&Y3[b * 131072 + jb * 32 + (tid << 2)];
                *(float4*)&sy[b * 1024 + (tid << 2)] = u;
            }
        }
        __syncthreads();

        // stage 1: s[b][di][dj] = sum_k X1[i][k] * X2[k][j]
        float s[NB][2][2] = {};
        #pragma unroll 8
        for (int k = 0; k < 32; k++) {
            #pragma unroll
            for (int b = 0; b < NB; b++) {
                const float2 a = *(const float2*)&sX1[b][k][ii * 2];
                const float2 v = *(const float2*)&sU[(b * 32 + k) * 32 + jj * 2];
                s[b][0][0] += a.x * v.x; s[b][0][1] += a.x * v.y;
                s[b][1][0] += a.y * v.x; s[b][1][1] += a.y * v.y;
            }
        }
        __syncthreads();                        // everyone done reading sU as X2

        // softmax over b (register-local), then write P = [b][j][i] into sU (stride 34)
        #pragma unroll
        for (int di = 0; di < 2; di++)
            #pragma unroll
            for (int dj = 0; dj < 2; dj++) {
                float s0 = s[0][di][dj], s1 = s[1][di][dj];
                float s2 = s[2][di][dj], s3 = s[3][di][dj];
                float m  = fmaxf(fmaxf(s0, s1), fmaxf(s2, s3));
                float e0 = __expf(s0 - m), e1 = __expf(s1 - m);
                float e2 = __expf(s2 - m), e3 = __expf(s3 - m);
                float r  = 1.0f / (e0 + e1 + e2 + e3);
                s[0][di][dj] = e0 * r; s[1][di][dj] = e1 * r;
                s[2][di][dj] = e2 * r; s[3][di][dj] = e3 * r;
            }
        #pragma unroll
        for (int b = 0; b < NB; b++)
            #pragma unroll
            for (int dj = 0; dj < 2; dj++)
                *(float2*)&sU[(b * 32 + jj * 2 + dj) * 34 + ii * 2] =
                    make_float2(s[b][0][dj], s[b][1][dj]);
        __syncthreads();

        // stage 2: O[b][i][c] += sum_kj P[b][kj][i] * Y3[b][kj][c]
        #pragma unroll 8
        for (int kj = 0; kj < 32; kj++) {
            #pragma unroll
            for (int b = 0; b < NB; b++) {
                const float2 p = *(const float2*)&sU[(b * 32 + kj) * 34 + ii * 2];
                const float2 y = *(const float2*)&sY3[b][kj][jj * 2];
                o_acc[b][0][0] += p.x * y.x; o_acc[b][0][1] += p.x * y.y;
                o_acc[b][1][0] += p.y * y.x; o_acc[b][1][1] += p.y * y.y;
            }
        }
    }

    // write this j-chunk's partial O
    float* op = OP + jc * 524288;
    #pragma unroll
    for (int b = 0; b < NB; b++)
        #pragma unroll
        for (int di = 0; di < 2; di++)
            *(float2*)&op[(b * 4096 + i0 + ii * 2 + di) * 32 + jj * 2] =
                make_float2(o_acc[b][di][0], o_acc[b][di][1]);
}

// reduce JS partials + conv4. O flat index ch*4096+hw is exactly y2[b][ch][hw].
__global__ __launch_bounds__(256) void out_kernel(
    const float* __restrict__ OP, const float* __restrict__ w4,
    const float* __restrict__ b4, float* __restrict__ out)
{
    __shared__ float sw[CIN][CHD];              // 8 KB
    __shared__ float sbias[CIN];
    const int tid = threadIdx.x;
    for (int e = tid; e < CIN * CHD; e += 256) sw[e >> 5][e & 31] = w4[e];
    if (tid < CIN) sbias[tid] = b4[tid];
    __syncthreads();

    const int b  = blockIdx.x >> 4;
    const int hw = ((blockIdx.x & 15) << 8) + tid;
    const int o0 = blockIdx.y * 32;

    float y2[CHD];
    #pragma unroll
    for (int ch = 0; ch < CHD; ch++) {
        float v = 0.f;
        #pragma unroll
        for (int p = 0; p < JS; p++)
            v += OP[p * 524288 + b * 131072 + ch * 4096 + hw];   // coalesced
        y2[ch] = v;
    }

    float* ob = out + b * CIN * N_PIX + hw;
    for (int o = o0; o < o0 + 32; o++) {
        float a0 = sbias[o], a1 = 0.f, a2 = 0.f, a3 = 0.f;
        #pragma unroll
        for (int c = 0; c < CHD; c += 4) {
            a0 += y2[c + 0] * sw[o][c + 0];
            a1 += y2[c + 1] * sw[o][c + 1];
            a2 += y2[c + 2] * sw[o][c + 2];
            a3 += y2[c + 3] * sw[o][c + 3];
        }
        ob[o * N_PIX] = (a0 + a1) + (a2 + a3);
    }
}

extern "C" void kernel_launch(void* const* d_in, const int* in_sizes, int n_in,
                              void* d_out, int out_size, void* d_ws, size_t ws_size,
                              hipStream_t stream) {
    const float* x  = (const float*)d_in[0];
    const float* w1 = (const float*)d_in[1];
    const float* b1 = (const float*)d_in[2];
    const float* w2 = (const float*)d_in[3];
    const float* b2 = (const float*)d_in[4];
    const float* w3 = (const float*)d_in[5];
    const float* b3 = (const float*)d_in[6];
    const float* w4 = (const float*)d_in[7];
    const float* b4 = (const float*)d_in[8];

    float* ws = (float*)d_ws;
    float* X1 = ws;
    float* X2 = ws + 524288;
    float* Y3 = ws + 1048576;
    float* OP = ws + 1572864;                   // JS*524288 floats
    float* out = (float*)d_out;

    dim3 g1(64, 3);
    convs_kernel<<<g1, 256, 0, stream>>>(x, w1, b1, w2, b2, w3, b3, X1, X2, Y3);
    attn_kernel<<<512, 256, 0, stream>>>(X1, X2, Y3, OP);
    dim3 g3(64, 2);
    out_kernel<<<g3, 256, 0, stream>>>(OP, w4, b4, out);
}

// Round 2
// 172.764 us; speedup vs baseline: 2.2435x; 2.2435x over previous
//
#include <hip/hip_runtime.h>

// NonLocalBlock, B=4, C=64, H=W=64, N=4096, Ch=32.  MFMA f16 version.
//
// Index algebra (verified round 1):
//  x1[b,i,k] = conv1_flat[b][i*32+k]  (raw reshape -> natural flat buffer)
//  x2[b,k,j] = conv2 natural [k][j]
//  y3[b,j,c] = conv3_flat[b][j*32+c]
//  attn[b,i,j] = sum_k x1*x2 ; softmax over BATCH axis (4 elems, per (i,j))
//  O[b,i,c] = sum_j attn*y3 ;  y2[b,ch,hw] = O_flat[b][ch*4096+hw] -> conv4
//
// MFMA plan (v_mfma_f32_16x16x32_f16, K=32 exact for both matmuls):
//  A-layout: A[m=lane&15][k=(lane>>4)*8+e]; B-layout: B[k=(lane>>4)*8+e][n=lane&15]
//  C-layout: col=lane&15, row=(lane>>4)*4+reg
//  Wave owns 16 i-rows x all 4 batches -> batch-softmax is register-local.
//  A1 from X1h[b][i][k] (k contig), B1 from X2t[b][j][k] (k contig),
//  B2 from Y3t[b][c][j] (j contig)  -> all 16B/lane global loads, NO barriers.
//  P transposed C->A layout via per-wave private LDS tile (stride 40 f16 = 80B,
//  16B aligned for ds_read_b128).
//  j split 16 ways; O accumulated with global atomicAdd (O memset per launch).

typedef _Float16 half8 __attribute__((ext_vector_type(8)));
typedef float f32x4 __attribute__((ext_vector_type(4)));

#define N_PIX 4096
#define CIN   64
#define CHD   32
#define NB    4
#define JS    16
#define TJ    32
#define ITERS ((N_PIX / JS) / TJ)   // 8
#define PSTR  40                    // f16 stride of P rows (80B, 16B-multiple)

// ws bytes: X1h @0 (1MB f16), X2t @1MB (1MB), Y3t @2MB (1MB), O @3MB (2MB f32)

__global__ __launch_bounds__(256) void convs_kernel(
    const float* __restrict__ x,
    const float* __restrict__ w1, const float* __restrict__ b1,
    const float* __restrict__ w2, const float* __restrict__ b2,
    const float* __restrict__ w3, const float* __restrict__ b3,
    _Float16* __restrict__ X1h, _Float16* __restrict__ X2t, _Float16* __restrict__ Y3t)
{
    const int t = blockIdx.y;                  // which conv (0..2)
    const float* w  = (t == 0) ? w1 : ((t == 1) ? w2 : w3);
    const float* bb = (t == 0) ? b1 : ((t == 1) ? b2 : b3);

    __shared__ float sw[CHD][CIN];             // 8 KB
    __shared__ float sbias[CHD];
    const int tid = threadIdx.x;
    for (int e = tid; e < CHD * CIN; e += 256) sw[e >> 6][e & 63] = w[e];
    if (tid < CHD) sbias[tid] = bb[tid];
    __syncthreads();

    const int b  = blockIdx.x >> 4;
    const int hw = ((blockIdx.x & 15) << 8) + tid;

    float xi[CIN];
    const float* xb = x + b * CIN * N_PIX + hw;
    #pragma unroll
    for (int c = 0; c < CIN; c++) xi[c] = xb[c * N_PIX];

    float out[CHD];
    for (int o = 0; o < CHD; o++) {
        float a0 = sbias[o], a1 = 0.f, a2 = 0.f, a3 = 0.f;
        #pragma unroll
        for (int c = 0; c < CIN; c += 4) {
            a0 += xi[c + 0] * sw[o][c + 0];
            a1 += xi[c + 1] * sw[o][c + 1];
            a2 += xi[c + 2] * sw[o][c + 2];
            a3 += xi[c + 3] * sw[o][c + 3];
        }
        out[o] = (a0 + a1) + (a2 + a3);
    }

    if (t == 0) {
        // X1h natural flat [ch][hw]  (== [i][k] after raw reshape)
        #pragma unroll
        for (int o = 0; o < CHD; o++)
            X1h[b * 131072 + o * N_PIX + hw] = (_Float16)out[o];
    } else if (t == 1) {
        // X2t[b][j=hw][k=ch]: 32 contiguous f16 per thread, as 4x half8
        #pragma unroll
        for (int mchunk = 0; mchunk < 4; mchunk++) {
            half8 v;
            #pragma unroll
            for (int e = 0; e < 8; e++) v[e] = (_Float16)out[mchunk * 8 + e];
            *(half8*)&X2t[b * 131072 + hw * 32 + mchunk * 8] = v;
        }
    } else {
        // Y3t[b][c][j]: y3 element of out[o] is (j = o*128 + (hw>>5), c = hw&31)
        const int c = hw & 31, jb = hw >> 5;
        #pragma unroll
        for (int o = 0; o < CHD; o++)
            Y3t[b * 131072 + c * N_PIX + o * 128 + jb] = (_Float16)out[o];
    }
}

__global__ __launch_bounds__(256) void attn_kernel(
    const _Float16* __restrict__ X1h, const _Float16* __restrict__ X2t,
    const _Float16* __restrict__ Y3t, float* __restrict__ O)
{
    __shared__ _Float16 sP[4 * NB * 16 * PSTR];   // 20480 B, per-wave private slices

    const int tid  = threadIdx.x;
    const int wv   = tid >> 6;
    const int lane = tid & 63;
    const int m    = lane & 15;
    const int q    = lane >> 4;
    const int i0   = (blockIdx.x * 4 + wv) * 16;
    const int jbase = blockIdx.y * (N_PIX / JS);

    _Float16* sPw = &sP[wv * NB * 16 * PSTR];

    // A1: X1 i-tile, all batches, loaded once (16B/lane, coalesced as a wave)
    half8 a1[NB];
    #pragma unroll
    for (int b = 0; b < NB; b++)
        a1[b] = *(const half8*)&X1h[b * 131072 + (i0 + m) * 32 + q * 8];

    f32x4 oacc[NB][2];
    #pragma unroll
    for (int b = 0; b < NB; b++) {
        oacc[b][0] = (f32x4){0.f, 0.f, 0.f, 0.f};
        oacc[b][1] = (f32x4){0.f, 0.f, 0.f, 0.f};
    }

    for (int it = 0; it < ITERS; it++) {
        const int j0 = jbase + it * TJ;

        // stage 1: S[b][i16][j32] = X1 x X2, 8 MFMAs
        f32x4 s[NB][2];
        #pragma unroll
        for (int b = 0; b < NB; b++)
            #pragma unroll
            for (int jh = 0; jh < 2; jh++) {
                half8 bf = *(const half8*)&X2t[(b * 4096 + j0 + jh * 16 + m) * 32 + q * 8];
                s[b][jh] = __builtin_amdgcn_mfma_f32_16x16x32_f16(
                    a1[b], bf, (f32x4){0.f, 0.f, 0.f, 0.f}, 0, 0, 0);
            }

        // softmax over batch (register-local; same C-layout for all b), write P
        #pragma unroll
        for (int jh = 0; jh < 2; jh++)
            #pragma unroll
            for (int r = 0; r < 4; r++) {
                float s0 = s[0][jh][r], s1 = s[1][jh][r];
                float s2 = s[2][jh][r], s3 = s[3][jh][r];
                float mx = fmaxf(fmaxf(s0, s1), fmaxf(s2, s3));
                float e0 = __expf(s0 - mx), e1 = __expf(s1 - mx);
                float e2 = __expf(s2 - mx), e3 = __expf(s3 - mx);
                float rs = 1.0f / (e0 + e1 + e2 + e3);
                const int base = (q * 4 + r) * PSTR + jh * 16 + m;  // [i_loc][j_loc]
                sPw[0 * 16 * PSTR + base] = (_Float16)(e0 * rs);
                sPw[1 * 16 * PSTR + base] = (_Float16)(e1 * rs);
                sPw[2 * 16 * PSTR + base] = (_Float16)(e2 * rs);
                sPw[3 * 16 * PSTR + base] = (_Float16)(e3 * rs);
            }

        // stage 2: O[b][i16][c32] += P x Y3, 8 MFMAs (A2 via ds_read_b128)
        #pragma unroll
        for (int b = 0; b < NB; b++) {
            half8 a2 = *(half8*)&sPw[b * 16 * PSTR + m * PSTR + q * 8];
            #pragma unroll
            for (int ch = 0; ch < 2; ch++) {
                half8 b2 = *(const half8*)&Y3t[b * 131072 + (ch * 16 + m) * N_PIX + j0 + q * 8];
                oacc[b][ch] = __builtin_amdgcn_mfma_f32_16x16x32_f16(a2, b2, oacc[b][ch], 0, 0, 0);
            }
        }
    }

    // accumulate partial O (j-chunk) into global
    #pragma unroll
    for (int b = 0; b < NB; b++)
        #pragma unroll
        for (int ch = 0; ch < 2; ch++)
            #pragma unroll
            for (int r = 0; r < 4; r++)
                atomicAdd(&O[b * 131072 + (i0 + q * 4 + r) * 32 + ch * 16 + m],
                          oacc[b][ch][r]);
}

// O flat index ch*4096+hw is exactly y2[b][ch][hw]; apply conv4.
__global__ __launch_bounds__(256) void out_kernel(
    const float* __restrict__ O, const float* __restrict__ w4,
    const float* __restrict__ b4, float* __restrict__ out)
{
    __shared__ float sw[CIN][CHD];              // 8 KB
    __shared__ float sbias[CIN];
    const int tid = threadIdx.x;
    for (int e = tid; e < CIN * CHD; e += 256) sw[e >> 5][e & 31] = w4[e];
    if (tid < CIN) sbias[tid] = b4[tid];
    __syncthreads();

    const int b  = blockIdx.x >> 4;
    const int hw = ((blockIdx.x & 15) << 8) + tid;
    const int o0 = blockIdx.y * 32;

    float y2[CHD];
    #pragma unroll
    for (int ch = 0; ch < CHD; ch++)
        y2[ch] = O[b * 131072 + ch * N_PIX + hw];   // coalesced

    float* ob = out + b * CIN * N_PIX + hw;
    for (int o = o0; o < o0 + 32; o++) {
        float a0 = sbias[o], a1 = 0.f, a2 = 0.f, a3 = 0.f;
        #pragma unroll
        for (int c = 0; c < CHD; c += 4) {
            a0 += y2[c + 0] * sw[o][c + 0];
            a1 += y2[c + 1] * sw[o][c + 1];
            a2 += y2[c + 2] * sw[o][c + 2];
            a3 += y2[c + 3] * sw[o][c + 3];
        }
        ob[o * N_PIX] = (a0 + a1) + (a2 + a3);
    }
}

extern "C" void kernel_launch(void* const* d_in, const int* in_sizes, int n_in,
                              void* d_out, int out_size, void* d_ws, size_t ws_size,
                              hipStream_t stream) {
    const float* x  = (const float*)d_in[0];
    const float* w1 = (const float*)d_in[1];
    const float* b1 = (const float*)d_in[2];
    const float* w2 = (const float*)d_in[3];
    const float* b2 = (const float*)d_in[4];
    const float* w3 = (const float*)d_in[5];
    const float* b3 = (const float*)d_in[6];
    const float* w4 = (const float*)d_in[7];
    const float* b4 = (const float*)d_in[8];

    char* wsb = (char*)d_ws;
    _Float16* X1h = (_Float16*)(wsb);
    _Float16* X2t = (_Float16*)(wsb + (1 << 20));
    _Float16* Y3t = (_Float16*)(wsb + (2 << 20));
    float*    O   = (float*)   (wsb + (3 << 20));
    float*    out = (float*)d_out;

    hipMemsetAsync(O, 0, 1 << 21, stream);      // O must start at zero (atomicAdd)

    dim3 g1(64, 3);
    convs_kernel<<<g1, 256, 0, stream>>>(x, w1, b1, w2, b2, w3, b3, X1h, X2t, Y3t);
    dim3 g2(64, JS);
    attn_kernel<<<g2, 256, 0, stream>>>(X1h, X2t, Y3t, O);
    dim3 g3(64, 2);
    out_kernel<<<g3, 256, 0, stream>>>(O, w4, b4, out);
}

// Round 3
// 145.599 us; speedup vs baseline: 2.6621x; 1.1866x over previous
//
#include <hip/hip_runtime.h>

// NonLocalBlock, B=4, C=64, H=W=64, N=4096, Ch=32.  MFMA f16, LDS-free hot loop.
//
// Index algebra (verified rounds 1-2):
//  x1[b,i,k] = conv1_flat[b][i*32+k]   (raw reshape of natural [ch][hw] buffer)
//  x2[b,k,j] = conv2 natural [k][j]
//  y3[b,j,c] = conv3_flat[b][j*32+c]
//  attn[b,i,j] = sum_k x1*x2 ; softmax over BATCH axis (4 elems, per (i,j))
//  O[b,i,c] = sum_j attn*y3 ;  y2[b,ch,hw] = O_flat[b][ch*4096+hw] -> conv4
//
// MFMA f16 16x16x32 layouts (HW-verified by round 2 passing):
//  A: A[m=lane&15][k=(lane>>4)*8+e]   B: B[k=(lane>>4)*8+e][n=lane&15]
//  C/D: row=(lane>>4)*4+reg, col=lane&15
//  => A-frag of M == B-frag of M^T (same lane data).
//
// Stage 1 computes S^T = mfma(A=x2 rows, B=x1) with PERMUTED x2 rows:
//  tile jh row m' loads X2 row j = (m'>>2)*8 + jh*4 + (m'&3).
//  Result: lane (q,m) holds P[i=m][j = q*8 + jh*4 + r] for jh in {0,1}, r in 0..3
//  = exactly the stage-2 B-operand fragment (k=q*8+e, e=jh*4+r). No transpose!
// Stage 2: O^T = mfma(A=Y3t rows (c), B=pfrag) -> lane (q,m): O[i=m][c=q*4+r+16ch],
//  4 consecutive c per lane -> float4 stores.

typedef _Float16 half8 __attribute__((ext_vector_type(8)));
typedef float f32x4 __attribute__((ext_vector_type(4)));

#define N_PIX 4096
#define CIN   64
#define CHD   32
#define NB    4
#define JS    4      // OP partial slices (blockIdx.y)

// ws bytes: X1h @0 (1MB f16), X2t @1MB (1MB), Y3t @2MB (1MB), OP @3MB (8MB f32) = 11MB

__global__ __launch_bounds__(256) void convs_kernel(
    const float* __restrict__ x,
    const float* __restrict__ w1, const float* __restrict__ b1,
    const float* __restrict__ w2, const float* __restrict__ b2,
    const float* __restrict__ w3, const float* __restrict__ b3,
    _Float16* __restrict__ X1h, _Float16* __restrict__ X2t, _Float16* __restrict__ Y3t)
{
    const int t = blockIdx.y;                  // which conv (0..2)
    const float* w  = (t == 0) ? w1 : ((t == 1) ? w2 : w3);
    const float* bb = (t == 0) ? b1 : ((t == 1) ? b2 : b3);

    __shared__ float sw[CHD][CIN];             // 8 KB
    __shared__ float sbias[CHD];
    __shared__ _Float16 sT[32 * 264];          // t==2 transpose tile (16.5 KB), c-stride 264
    const int tid = threadIdx.x;
    for (int e = tid; e < CHD * CIN; e += 256) sw[e >> 6][e & 63] = w[e];
    if (tid < CHD) sbias[tid] = bb[tid];
    __syncthreads();

    const int b  = blockIdx.x >> 4;
    const int hw = ((blockIdx.x & 15) << 8) + tid;

    float xi[CIN];
    const float* xb = x + b * CIN * N_PIX + hw;
    #pragma unroll
    for (int c = 0; c < CIN; c++) xi[c] = xb[c * N_PIX];

    float out[CHD];
    for (int o = 0; o < CHD; o++) {
        float a0 = sbias[o], a1 = 0.f, a2 = 0.f, a3 = 0.f;
        #pragma unroll
        for (int c = 0; c < CIN; c += 4) {
            a0 += xi[c + 0] * sw[o][c + 0];
            a1 += xi[c + 1] * sw[o][c + 1];
            a2 += xi[c + 2] * sw[o][c + 2];
            a3 += xi[c + 3] * sw[o][c + 3];
        }
        out[o] = (a0 + a1) + (a2 + a3);
    }

    if (t == 0) {
        // X1h natural flat [ch][hw]  (== [i][k] under raw reshape)
        #pragma unroll
        for (int o = 0; o < CHD; o++)
            X1h[b * 131072 + o * N_PIX + hw] = (_Float16)out[o];
    } else if (t == 1) {
        // X2t[b][j=hw][k=ch]: 32 contiguous f16 per thread
        #pragma unroll
        for (int mc = 0; mc < 4; mc++) {
            half8 v;
            #pragma unroll
            for (int e = 0; e < 8; e++) v[e] = (_Float16)out[mc * 8 + e];
            *(half8*)&X2t[b * 131072 + hw * 32 + mc * 8] = v;
        }
    } else {
        // Y3t[b][c][j], element of out[o]: c = hw&31, j = o*128 + (hw>>5).
        // Stage through LDS so global stores are contiguous half8.
        const int c  = tid & 31;
        const int jl = tid >> 5;               // 0..7
        #pragma unroll
        for (int o = 0; o < CHD; o++)
            sT[c * 264 + o * 8 + jl] = (_Float16)out[o];
        __syncthreads();
        const int jb0 = (blockIdx.x & 15) << 3;   // base (hw>>5) for this block
        #pragma unroll
        for (int g = 0; g < 4; g++) {
            int u  = g * 256 + tid;
            int c2 = (u >> 5) & 31;
            int o2 = u & 31;
            half8 v = *(half8*)&sT[c2 * 264 + o2 * 8];
            *(half8*)&Y3t[b * 131072 + c2 * 4096 + o2 * 128 + jb0] = v;
        }
    }
}

__global__ __launch_bounds__(256) void attn_kernel(
    const _Float16* __restrict__ X1h, const _Float16* __restrict__ X2t,
    const _Float16* __restrict__ Y3t, float* __restrict__ OP)
{
    __shared__ float sRed[4 * 64 * 64];        // [wave][f][lane], 64 KB (2 blocks/CU)

    const int tid  = threadIdx.x;
    const int wv   = tid >> 6;
    const int lane = tid & 63;
    const int m    = lane & 15;
    const int q    = lane >> 4;
    const int ip   = blockIdx.x;               // 0..127: i-pair (32 rows)
    const int js   = blockIdx.y;               // 0..3
    const int i0   = ip * 32;
    const int jbase = js * 1024 + wv * 256;    // wave-private j range (8 iters x 32)

    // stage-1 B-frags: x1[i0+il*16+m][k=q*8..], preloaded (A-frag data of x1)
    half8 bx1[NB][2];
    #pragma unroll
    for (int b = 0; b < NB; b++)
        #pragma unroll
        for (int il = 0; il < 2; il++)
            bx1[b][il] = *(const half8*)&X1h[b * 131072 + (i0 + il * 16 + m) * 32 + q * 8];

    f32x4 oaccT[NB][2][2];                     // [b][ch][il], lane: O^T[c][i]
    #pragma unroll
    for (int b = 0; b < NB; b++)
        #pragma unroll
        for (int ch = 0; ch < 2; ch++)
            #pragma unroll
            for (int il = 0; il < 2; il++)
                oaccT[b][ch][il] = (f32x4){0.f, 0.f, 0.f, 0.f};

    const int jrow0 = ((m >> 2) * 8) + (m & 3);   // permuted A-row base (+ jh*4)

    #pragma unroll 2
    for (int jt = 0; jt < 8; jt++) {
        const int j0 = jbase + jt * 32;

        // fragment loads for this iter (16x dwordx4, no LDS)
        half8 ax2[NB][2], ay3[NB][2];
        #pragma unroll
        for (int b = 0; b < NB; b++) {
            #pragma unroll
            for (int jh = 0; jh < 2; jh++)
                ax2[b][jh] = *(const half8*)&X2t[b * 131072 + (j0 + jrow0 + jh * 4) * 32 + q * 8];
            #pragma unroll
            for (int ch = 0; ch < 2; ch++)
                ay3[b][ch] = *(const half8*)&Y3t[b * 131072 + (ch * 16 + m) * 4096 + j0 + q * 8];
        }

        #pragma unroll
        for (int il = 0; il < 2; il++) {
            // stage 1: S^T tiles (permuted rows)
            f32x4 sT[NB][2];
            #pragma unroll
            for (int b = 0; b < NB; b++)
                #pragma unroll
                for (int jh = 0; jh < 2; jh++)
                    sT[b][jh] = __builtin_amdgcn_mfma_f32_16x16x32_f16(
                        ax2[b][jh], bx1[b][il], (f32x4){0.f, 0.f, 0.f, 0.f}, 0, 0, 0);

            // softmax over batch (register-local), pack stage-2 B-frag in-lane
            half8 pf[NB];
            #pragma unroll
            for (int jh = 0; jh < 2; jh++)
                #pragma unroll
                for (int r = 0; r < 4; r++) {
                    float s0 = sT[0][jh][r], s1 = sT[1][jh][r];
                    float s2 = sT[2][jh][r], s3 = sT[3][jh][r];
                    float mx = fmaxf(fmaxf(s0, s1), fmaxf(s2, s3));
                    float e0 = __expf(s0 - mx), e1 = __expf(s1 - mx);
                    float e2 = __expf(s2 - mx), e3 = __expf(s3 - mx);
                    float rs = 1.0f / (e0 + e1 + e2 + e3);
                    pf[0][jh * 4 + r] = (_Float16)(e0 * rs);
                    pf[1][jh * 4 + r] = (_Float16)(e1 * rs);
                    pf[2][jh * 4 + r] = (_Float16)(e2 * rs);
                    pf[3][jh * 4 + r] = (_Float16)(e3 * rs);
                }

            // stage 2: O^T += Y3^T x P^T
            #pragma unroll
            for (int b = 0; b < NB; b++)
                #pragma unroll
                for (int ch = 0; ch < 2; ch++)
                    oaccT[b][ch][il] = __builtin_amdgcn_mfma_f32_16x16x32_f16(
                        ay3[b][ch], pf[b], oaccT[b][ch][il], 0, 0, 0);
        }
    }

    // cross-wave reduction (4 j-subchunks -> one OP slice). f = b*16+ch*8+il*4+r.
    #pragma unroll
    for (int b = 0; b < NB; b++)
        #pragma unroll
        for (int ch = 0; ch < 2; ch++)
            #pragma unroll
            for (int il = 0; il < 2; il++)
                #pragma unroll
                for (int r = 0; r < 4; r++)
                    sRed[(wv * 64 + b * 16 + ch * 8 + il * 4 + r) * 64 + lane] =
                        oaccT[b][ch][il][r];
    __syncthreads();

    const int br = wv;                         // wave handles batch b=wv
    float* op = OP + js * 524288 + (br * 4096 + i0) * 32;
    #pragma unroll
    for (int ch = 0; ch < 2; ch++)
        #pragma unroll
        for (int il = 0; il < 2; il++) {
            f32x4 v;
            #pragma unroll
            for (int r = 0; r < 4; r++) {
                int f = br * 16 + ch * 8 + il * 4 + r;
                v[r] = sRed[(0 * 64 + f) * 64 + lane] + sRed[(1 * 64 + f) * 64 + lane]
                     + sRed[(2 * 64 + f) * 64 + lane] + sRed[(3 * 64 + f) * 64 + lane];
            }
            *(f32x4*)&op[(il * 16 + m) * 32 + ch * 16 + q * 4] = v;
        }
}

// reduce JS partials + conv4. O flat index ch*4096+hw is exactly y2[b][ch][hw].
__global__ __launch_bounds__(256) void out_kernel(
    const float* __restrict__ OP, const float* __restrict__ w4,
    const float* __restrict__ b4, float* __restrict__ out)
{
    __shared__ float sw[CIN][CHD];             // 8 KB
    __shared__ float sbias[CIN];
    const int tid = threadIdx.x;
    for (int e = tid; e < CIN * CHD; e += 256) sw[e >> 5][e & 31] = w4[e];
    if (tid < CIN) sbias[tid] = b4[tid];
    __syncthreads();

    const int b  = blockIdx.x >> 4;
    const int hw = ((blockIdx.x & 15) << 8) + tid;
    const int o0 = blockIdx.y * 32;

    float y2[CHD];
    #pragma unroll
    for (int ch = 0; ch < CHD; ch++) {
        float v = 0.f;
        #pragma unroll
        for (int p = 0; p < JS; p++)
            v += OP[p * 524288 + b * 131072 + ch * 4096 + hw];   // coalesced
        y2[ch] = v;
    }

    float* ob = out + b * CIN * N_PIX + hw;
    for (int o = o0; o < o0 + 32; o++) {
        float a0 = sbias[o], a1 = 0.f, a2 = 0.f, a3 = 0.f;
        #pragma unroll
        for (int c = 0; c < CHD; c += 4) {
            a0 += y2[c + 0] * sw[o][c + 0];
            a1 += y2[c + 1] * sw[o][c + 1];
            a2 += y2[c + 2] * sw[o][c + 2];
            a3 += y2[c + 3] * sw[o][c + 3];
        }
        ob[o * N_PIX] = (a0 + a1) + (a2 + a3);
    }
}

extern "C" void kernel_launch(void* const* d_in, const int* in_sizes, int n_in,
                              void* d_out, int out_size, void* d_ws, size_t ws_size,
                              hipStream_t stream) {
    const float* x  = (const float*)d_in[0];
    const float* w1 = (const float*)d_in[1];
    const float* b1 = (const float*)d_in[2];
    const float* w2 = (const float*)d_in[3];
    const float* b2 = (const float*)d_in[4];
    const float* w3 = (const float*)d_in[5];
    const float* b3 = (const float*)d_in[6];
    const float* w4 = (const float*)d_in[7];
    const float* b4 = (const float*)d_in[8];

    char* wsb = (char*)d_ws;
    _Float16* X1h = (_Float16*)(wsb);
    _Float16* X2t = (_Float16*)(wsb + (1 << 20));
    _Float16* Y3t = (_Float16*)(wsb + (2 << 20));
    float*    OP  = (float*)   (wsb + (3 << 20));   // JS x 2MB
    float*    out = (float*)d_out;

    dim3 g1(64, 3);
    convs_kernel<<<g1, 256, 0, stream>>>(x, w1, b1, w2, b2, w3, b3, X1h, X2t, Y3t);
    dim3 g2(128, JS);
    attn_kernel<<<g2, 256, 0, stream>>>(X1h, X2t, Y3t, OP);
    dim3 g3(64, 2);
    out_kernel<<<g3, 256, 0, stream>>>(OP, w4, b4, out);
}